// Round 1
// 770.301 us; speedup vs baseline: 1.1399x; 1.1399x over previous
//
#include <hip/hip_runtime.h>

// BuildCost: light-field cost volume
//   x:    [1, 32, 81, 192, 192] fp32
//   mask: [1, 81, 192, 192]     fp32
//   W:    [128, 81]             fp32   (grouped 1x1, groups=32, m=4 per group)
//   out:  [1, 128, 9, 192, 192] fp32
//
// out[c*4+m, d+4, i, j] = (81/sum_t mask[t,i,j]) *
//     sum_{p,q} x[c, p*9+q, i+(4-p)*d, j+(4-q)*d] * mask[p*9+q, i, j] * W[c*4+m, p*9+q]
// with out-of-bounds x reads = 0 (zero padding).
//
// v2: LDS double-buffered halo staging. The previous version issued 10 scalar
// global loads per tap with a vmcnt(0) before the FMA block -> latency-bound
// (VALUBusy 32%, HBM 23%). Now each tap's 48x48 halo region is staged into LDS
// as aligned float4s (2.25 loads/thread), loads for tap t+1 issued BEFORE the
// FMA consume of tap t (latency hidden under compute), ds_write after consume,
// one barrier per tap. Border zero-fill is baked into the staged tile, so the
// main loop has no bounds predicates for any block.

#define AA   81
#define HH   192
#define WW   192
#define HW   (HH * WW)
#define NC   32
#define MM   4
#define ND   9

#define RG      48                 // staged region: 16 + 2*16 halo
#define RITEMS  (RG * RG / 4)      // 576 float4 items per tap

__global__ __launch_bounds__(256)
void buildcost_kernel(const float* __restrict__ x,
                      const float* __restrict__ mask,
                      const float* __restrict__ Wt,
                      float* __restrict__ out) {
    __shared__ float  wlds[AA * MM];
    __shared__ float4 buf[2][RITEMS];   // double-buffered 48x48 fp32 region

    const int lin  = blockIdx.x;
    const int xcd  = lin & 7;
    const int slot = lin >> 3;          // [0, 576)
    const int cgrp = slot / 144;        // [0, 4)
    const int sp   = slot - cgrp * 144; // [0, 144)
    const int c    = xcd + (cgrp << 3);
    const int by   = sp / 12;
    const int bx   = sp - by * 12;

    const int tid = threadIdx.x;
    const int tx  = tid & 15;
    const int ty  = tid >> 4;
    const int j   = bx * 16 + tx;
    const int i   = by * 16 + ty;
    const int pix = i * WW + j;

    // Stage weights transposed: wlds[t*4+m] = W[(c*4+m)*81 + t]
    for (int idx = tid; idx < AA * MM; idx += 256) {
        const int t = idx >> 2;
        const int m = idx & 3;
        wlds[idx] = Wt[(c * MM + m) * AA + t];
    }

    // ---- per-thread staged-item precompute (tap-independent) ----
    // item k covers region floats [k*4, k*4+4): row = k/12, col = (k%12)*4.
    // Region origin in the image: (by*16-16, bx*16-16). Columns are 16B-aligned.
    const int y0 = by * 16 - 16;
    const int x0 = bx * 16 - 16;

    int off0, off1, off2;
    bool v0, v1, v2;
    {
        const int i0 = tid,        r0 = i0 / 12, c0 = (i0 - r0 * 12) * 4;
        const int i1 = tid + 256,  r1 = i1 / 12, c1 = (i1 - r1 * 12) * 4;
        const int i2 = tid + 512,  r2 = i2 / 12, c2 = (i2 - r2 * 12) * 4;
        const int gy0 = y0 + r0, gx0 = x0 + c0;
        const int gy1 = y0 + r1, gx1 = x0 + c1;
        const int gy2 = y0 + r2, gx2 = x0 + c2;
        v0 = ((unsigned)gy0 < (unsigned)HH) & ((unsigned)gx0 < (unsigned)WW);
        v1 = ((unsigned)gy1 < (unsigned)HH) & ((unsigned)gx1 < (unsigned)WW);
        v2 = (i2 < RITEMS) & ((unsigned)gy2 < (unsigned)HH) & ((unsigned)gx2 < (unsigned)WW);
        off0 = v0 ? (gy0 * WW + gx0) : 0;
        off1 = v1 ? (gy1 * WW + gx1) : 0;
        off2 = v2 ? (gy2 * WW + gx2) : 0;
    }
    const bool interior = (bx >= 1) & (bx <= 10) & (by >= 1) & (by <= 10);

    const float* __restrict__ xc = x + (size_t)c * AA * HW;

    float4 s0, s1, s2;
    const float4 zf4 = {0.f, 0.f, 0.f, 0.f};

#define STAGE_LOAD(XT)                                                  \
    do {                                                                \
        if (interior) {                                                 \
            s0 = *(const float4*)((XT) + off0);                         \
            s1 = *(const float4*)((XT) + off1);                         \
            s2 = zf4;                                                   \
            if (tid < 64) s2 = *(const float4*)((XT) + off2);           \
        } else {                                                        \
            s0 = zf4; s1 = zf4; s2 = zf4;                               \
            if (v0) s0 = *(const float4*)((XT) + off0);                 \
            if (v1) s1 = *(const float4*)((XT) + off1);                 \
            if (v2) s2 = *(const float4*)((XT) + off2);                 \
        }                                                               \
    } while (0)

    float acc[ND][MM];
#pragma unroll
    for (int dd = 0; dd < ND; ++dd)
#pragma unroll
        for (int m = 0; m < MM; ++m) acc[dd][m] = 0.f;

    // ---- prologue: stage tap 0 into buf[0], prefetch mask[0] ----
    const float* __restrict__ xt = xc;
    STAGE_LOAD(xt);
    {
        float4* wb = &buf[0][0];
        wb[tid]       = s0;
        wb[tid + 256] = s1;
        if (tid < 64) wb[tid + 512] = s2;
    }
    float mval_next = mask[pix];
    __syncthreads();

    const int lbase = (ty + 16) * RG + (tx + 16);
    float msum = 0.f;
    int p = 0, q = 0;
    int cur = 0;

#pragma unroll 1
    for (int t = 0; t < AA; ++t) {
        const float mval = mval_next;
        const bool  more = (t + 1 < AA);

        // issue next tap's global loads BEFORE consuming this tap (latency
        // hidden under the FMA block below)
        if (more) {
            xt += HW;
            STAGE_LOAD(xt);
            mval_next = mask[(size_t)(t + 1) * HW + pix];
        }

        msum += mval;
        const float4 w4 = *(const float4*)&wlds[t * 4];
        const int kp = 4 - p;
        const int kq = 4 - q;
        const int lstep = kp * RG + kq;      // LDS word delta per +1 in d
        const float* lb = (const float*)&buf[cur][0];

#pragma unroll
        for (int dd = 0; dd < ND; ++dd) {
            const float v = lb[lbase + (dd - 4) * lstep];
            const float s = v * mval;
            acc[dd][0] += s * w4.x;
            acc[dd][1] += s * w4.y;
            acc[dd][2] += s * w4.z;
            acc[dd][3] += s * w4.w;
        }

        // write next tap into the other buffer (compiler inserts the vmcnt
        // wait here, after ~300 cycles of consume work)
        if (more) {
            float4* wb = &buf[cur ^ 1][0];
            wb[tid]       = s0;
            wb[tid + 256] = s1;
            if (tid < 64) wb[tid + 512] = s2;
        }
        __syncthreads();
        cur ^= 1;
        if (++q == 9) { q = 0; ++p; }
    }

    const float inv = (float)AA / msum;

#pragma unroll
    for (int m = 0; m < MM; ++m)
#pragma unroll
        for (int dd = 0; dd < ND; ++dd)
            out[((size_t)(c * MM + m) * ND + dd) * HW + pix] = acc[dd][m] * inv;
}

extern "C" void kernel_launch(void* const* d_in, const int* in_sizes, int n_in,
                              void* d_out, int out_size, void* d_ws, size_t ws_size,
                              hipStream_t stream) {
    const float* x    = (const float*)d_in[0];
    const float* mask = (const float*)d_in[1];
    const float* Wt   = (const float*)d_in[2];
    float* out        = (float*)d_out;

    dim3 grid(12 * 12 * NC);
    dim3 block(256);
    buildcost_kernel<<<grid, block, 0, stream>>>(x, mask, Wt, out);
}